// Round 1
// baseline (2477.656 us; speedup 1.0000x reference)
//
#include <hip/hip_runtime.h>

#define H 64
#define T_STEPS 2048

typedef _Float16 h2_t __attribute__((ext_vector_type(2)));
typedef _Float16 h8_t __attribute__((ext_vector_type(8)));

__device__ __forceinline__ float tanh_f(float x) {
    return 2.0f / (1.0f + __expf(-2.0f * x)) - 1.0f;
}

#if __has_builtin(__builtin_amdgcn_fdot2)
__device__ __forceinline__ float dot2(h2_t a, h2_t b, float c) {
    return __builtin_amdgcn_fdot2(a, b, c, false);
}
#else
__device__ __forceinline__ float dot2(h2_t a, h2_t b, float c) {
    float r;
    asm volatile("v_dot2_f32_f16 %0, %1, %2, %3"
                 : "=v"(r) : "v"(a), "v"(b), "v"(c));
    return r;
}
#endif

#define SUB2(v, i) __builtin_shufflevector((v), (v), (i), (i) + 1)

__device__ __forceinline__ float d8(h8_t wv, h8_t hv, float acc) {
    acc = dot2(SUB2(wv, 0), SUB2(hv, 0), acc);
    acc = dot2(SUB2(wv, 2), SUB2(hv, 2), acc);
    acc = dot2(SUB2(wv, 4), SUB2(hv, 4), acc);
    acc = dot2(SUB2(wv, 6), SUB2(hv, 6), acc);
    return acc;
}

// 64-wide dot: FOUR independent 8-dot2 chains (R14: shorter dep chains
// than R13's 2x16; needs 4 live accumulators, we now have the regs).
#define DOTROW8(Wa, Wb, Wc, Wd, We, Wf, Wg, Wh, hp)                       \
    ((d8(Wb, (hp)[1], d8(Wa, (hp)[0], 0.f))                               \
    + d8(Wd, (hp)[3], d8(Wc, (hp)[2], 0.f)))                              \
   + (d8(Wf, (hp)[5], d8(We, (hp)[4], 0.f))                               \
    + d8(Wh, (hp)[7], d8(Wg, (hp)[6], 0.f))))

// 32-wide dot (L0 half-row): two independent 8-chains
#define DOTROW4(Wa, Wb, Wc, Wd, hp)                                       \
    (d8(Wb, (hp)[1], d8(Wa, (hp)[0], 0.f))                                \
   + d8(Wd, (hp)[3], d8(Wc, (hp)[2], 0.f)))

// load 16 fp32 weights -> two h8_t (load-time only)
__device__ __forceinline__ void cvt16(const float* __restrict__ src,
                                      h8_t& a, h8_t& b) {
    const float4* p = (const float4*)src;
    float4 v0 = p[0], v1 = p[1], v2 = p[2], v3 = p[3];
    a[0] = (_Float16)v0.x; a[1] = (_Float16)v0.y;
    a[2] = (_Float16)v0.z; a[3] = (_Float16)v0.w;
    a[4] = (_Float16)v1.x; a[5] = (_Float16)v1.y;
    a[6] = (_Float16)v1.z; a[7] = (_Float16)v1.w;
    b[0] = (_Float16)v2.x; b[1] = (_Float16)v2.y;
    b[2] = (_Float16)v2.z; b[3] = (_Float16)v2.w;
    b[4] = (_Float16)v3.x; b[5] = (_Float16)v3.y;
    b[6] = (_Float16)v3.z; b[7] = (_Float16)v3.w;
}

// branchless activation + in-wave gate gather + cell update.
// pre: this row's full pre-activation (identical on both half-lanes).
// isg/b0/b1 derive from gate = (l>>4)&3; gather via xor 16/32/48 as R13.
__device__ __forceinline__ float cell_update(float pre, bool isg,
                                             bool b0, bool b1, float& cst) {
    float zz  = isg ? (-2.0f * pre) : (-pre);
    float ex  = __expf(zz);
    float rr  = 1.0f / (1.0f + ex);
    float act = isg ? (2.0f * rr - 1.0f) : rr;
    float a16 = __shfl_xor(act, 16);   // gate^1
    float a32 = __shfl_xor(act, 32);   // gate^2
    float a48 = __shfl_xor(act, 48);   // gate^3
    float q0 = b0 ? a16 : act, q1 = b0 ? act : a16;
    float q2 = b0 ? a48 : a32, q3 = b0 ? a32 : a48;
    float gi = b1 ? q2 : q0;           // i
    float gf = b1 ? q3 : q1;           // f
    float gg = b1 ? q0 : q2;           // g
    float go = b1 ? q1 : q3;           // o
    cst = gf * cst + gi * gg;
    return go * tanh_f(cst);
}

// R14: LANE-PAIR ROW SPLIT, 1024 THREADS, 128-VGPR BUDGET.
// R13 pinned 64 weight-VGPRs/lane against a ~72-VGPR allocation -> the
// compiler had no headroom for the 16 LDS h-fragments and serialized
// ds_read->dot (and/or spilled), giving ~2810 cyc/step vs ~750 ideal.
// R14 halves persistent weights per lane:
//   16 waves. Lane l: hf=l&1 (row half), gate=(l>>4)&3, rw=(l>>1)&7,
//   cell=(w&7)*8+rw, row=gate*64+cell.
//   waves 0-7 : L1 half-row (hf=0: Wih1 vs h_prev-layer, hf=1: Whh1 vs own h)
//               = 8 h8 = 32 VGPR; PLUS L0 half-row (Whh0 cols [hf*32,+32))
//               = 4 h8 = 16 VGPR; x-term folded into hf=0 lane (zero-weight
//               trick on hf=1). Persistent ~54 VGPR.
//   waves 8-15: L2 half-row = 32 VGPR. Persistent ~40 VGPR.
// Halves combine with one __shfl_xor(part,1); gate gather unchanged.
// __launch_bounds__(1024,4): 16 waves = exactly 4/EU -> 128-VGPR budget,
// so h-fragments can be fully prefetched. Same slot scheme / 1 barrier
// per phase; layer pipeline L0:t=p, L1:t=p-1, L2:t=p-2.
__global__ __launch_bounds__(1024, 4)
void lstm3_r14(const float* __restrict__ x,
               const float* __restrict__ Wih0, const float* __restrict__ Whh0,
               const float* __restrict__ bih0, const float* __restrict__ bhh0,
               const float* __restrict__ Wih1, const float* __restrict__ Whh1,
               const float* __restrict__ bih1, const float* __restrict__ bhh1,
               const float* __restrict__ Wih2, const float* __restrict__ Whh2,
               const float* __restrict__ bih2, const float* __restrict__ bhh2,
               const float* __restrict__ Wout, const float* __restrict__ bout,
               float* __restrict__ out)
{
    __shared__ __align__(16) float xs[T_STEPS * 2];       // 16 KB input seq
    __shared__ __align__(16) _Float16 h0b[2][H];
    __shared__ __align__(16) _Float16 h1b[2][H];
    __shared__ __align__(16) _Float16 h2b[2][H];
    __shared__ __align__(16) float h2f[H];

    const int tid  = threadIdx.x;
    const int b    = blockIdx.x;
    const int w    = tid >> 6;               // wave 0..15
    const int l    = tid & 63;
    const int hf   = l & 1;                  // row half
    const int gate = (l >> 4) & 3;           // 0:i 1:f 2:g 3:o
    const int cell = (w & 7) * 8 + ((l >> 1) & 7);
    const int row  = gate * H + cell;        // gate row 0..255
    const bool isL01 = (w < 8);              // wave-uniform
    const bool isg = (gate == 2);
    const bool b0g = (gate & 1) != 0, b1g = (gate & 2) != 0;

    // ---- stage x[b,:,:]: exactly one float4 per thread ----
    ((float4*)xs)[tid] = ((const float4*)(x + (size_t)b * T_STEPS * 2))[tid];

    // ---- weights: half-row(s) for this lane ----
    h8_t W0, W1, W2, W3, W4, W5, W6, W7;   // L1 or L2 half-row (64 w)
    h8_t X0, X1, X2, X3;                   // L0 half-row (32 w), waves 0-7
    float wx0 = 0.f, wx1 = 0.f, biasL = 0.f, bias0 = 0.f;
    if (isL01) {
        const float* m = (hf ? Whh1 : Wih1) + row * H;
        cvt16(m,      W0, W1); cvt16(m + 16, W2, W3);
        cvt16(m + 32, W4, W5); cvt16(m + 48, W6, W7);
        const float* m0 = Whh0 + row * H + hf * 32;
        cvt16(m0, X0, X1); cvt16(m0 + 16, X2, X3);
        if (!hf) { wx0 = Wih0[row * 2]; wx1 = Wih0[row * 2 + 1]; }
        biasL = bih1[row] + bhh1[row];
        bias0 = bih0[row] + bhh0[row];
    } else {
        const float* m = (hf ? Whh2 : Wih2) + row * H;
        cvt16(m,      W0, W1); cvt16(m + 16, W2, W3);
        cvt16(m + 32, W4, W5); cvt16(m + 48, W6, W7);
        biasL = bih2[row] + bhh2[row];
#pragma unroll
        for (int i = 0; i < 8; ++i) {      // defined values for the pins
            X0[i] = (_Float16)0.f; X1[i] = (_Float16)0.f;
            X2[i] = (_Float16)0.f; X3[i] = (_Float16)0.f;
        }
    }
    // pin to stop rematerialization of the fp32->fp16 conversion in-loop
    asm volatile("" : "+v"(W0), "+v"(W1), "+v"(W2), "+v"(W3));
    asm volatile("" : "+v"(W4), "+v"(W5), "+v"(W6), "+v"(W7));
    asm volatile("" : "+v"(X0), "+v"(X1), "+v"(X2), "+v"(X3));
    asm volatile("" : "+v"(wx0), "+v"(wx1), "+v"(biasL), "+v"(bias0));

    if (tid < H) {
        _Float16 z = (_Float16)0.f;
        h0b[0][tid] = z; h0b[1][tid] = z;
        h1b[0][tid] = z; h1b[1][tid] = z;
        h2b[0][tid] = z; h2b[1][tid] = z;
    }
    float cstL = 0.f, cst0 = 0.f;   // per-lane cell-state copies
    __syncthreads();

#pragma unroll 1
    for (int p = 0; p < T_STEPS + 2; ++p) {
        const int s  = (p + 1) & 1;    // read slot
        const int wr = p & 1;          // write slot
        if (isL01) {
            if (p < T_STEPS) {         // ---- L0, t = p ----
                const h8_t* hp = (const h8_t*)&h0b[s][hf * 32];
                float2 xt = *(const float2*)&xs[2 * p];
                float part = DOTROW4(X0, X1, X2, X3, hp)
                           + wx0 * xt.x + wx1 * xt.y;   // 0 on hf=1 lanes
                part += __shfl_xor(part, 1);            // combine halves
                float hh = cell_update(part + bias0, isg, b0g, b1g, cst0);
                if ((l & 49) == 0)                      // gate==0 && hf==0
                    h0b[wr][cell] = (_Float16)hh;
            }
            if (p >= 1 && p <= T_STEPS) {   // ---- L1, t = p-1 ----
                const h8_t* hp = (const h8_t*)(hf ? h1b[s] : h0b[s]);
                float part = DOTROW8(W0, W1, W2, W3, W4, W5, W6, W7, hp);
                part += __shfl_xor(part, 1);
                float hh = cell_update(part + biasL, isg, b0g, b1g, cstL);
                if ((l & 49) == 0)
                    h1b[wr][cell] = (_Float16)hh;
            }
        } else {
            if (p >= 2) {                   // ---- L2, t = p-2 ----
                const h8_t* hp = (const h8_t*)(hf ? h2b[s] : h1b[s]);
                float part = DOTROW8(W0, W1, W2, W3, W4, W5, W6, W7, hp);
                part += __shfl_xor(part, 1);
                float hh = cell_update(part + biasL, isg, b0g, b1g, cstL);
                if ((l & 49) == 0) {
                    h2b[wr][cell] = (_Float16)hh;
                    if (p == T_STEPS + 1) h2f[cell] = hh;  // final h only
                }
            }
        }
        __syncthreads();
    }

    // ---- fused projection: out[b,:] = h2_last @ Wout^T + bout ----
    if (tid < 11) {
        float acc = bout[tid];
#pragma unroll
        for (int jj = 0; jj < H; ++jj)
            acc += Wout[tid * H + jj] * h2f[jj];
        out[b * 11 + tid] = acc;
    }
}

extern "C" void kernel_launch(void* const* d_in, const int* in_sizes, int n_in,
                              void* d_out, int out_size, void* d_ws, size_t ws_size,
                              hipStream_t stream) {
    const float* x    = (const float*)d_in[0];
    const float* Wih0 = (const float*)d_in[1];
    const float* Whh0 = (const float*)d_in[2];
    const float* bih0 = (const float*)d_in[3];
    const float* bhh0 = (const float*)d_in[4];
    const float* Wih1 = (const float*)d_in[5];
    const float* Whh1 = (const float*)d_in[6];
    const float* bih1 = (const float*)d_in[7];
    const float* bhh1 = (const float*)d_in[8];
    const float* Wih2 = (const float*)d_in[9];
    const float* Whh2 = (const float*)d_in[10];
    const float* bih2 = (const float*)d_in[11];
    const float* bhh2 = (const float*)d_in[12];
    const float* Wout = (const float*)d_in[13];
    const float* bout = (const float*)d_in[14];
    float* out = (float*)d_out;

    lstm3_r14<<<256, 1024, 0, stream>>>(x,
        Wih0, Whh0, bih0, bhh0,
        Wih1, Whh1, bih1, bhh1,
        Wih2, Whh2, bih2, bhh2,
        Wout, bout, out);
}